// Round 2
// baseline (1640.150 us; speedup 1.0000x reference)
//
#include <hip/hip_runtime.h>

#define BR 64
#define BC 64
#define KH 64

// ---------------- CSR build ----------------
__global__ void k_hist(const int* __restrict__ dst, int* __restrict__ deg, int E) {
  int e = blockIdx.x * blockDim.x + threadIdx.x;
  if (e < E) atomicAdd(&deg[dst[e]], 1);
}

// off[v] = start slot for node v (order irrelevant, only contiguity needed)
__global__ void k_alloc(const int* __restrict__ deg, int* __restrict__ off,
                        int* __restrict__ cursor, int* __restrict__ counter, int N) {
  int v = blockIdx.x * blockDim.x + threadIdx.x;
  int lane = threadIdx.x & 63;
  int d = (v < N) ? deg[v] : 0;
  int pre = d;
  #pragma unroll
  for (int s = 1; s < 64; s <<= 1) {
    int t = __shfl_up(pre, s);
    if (lane >= s) pre += t;
  }
  int total = __shfl(pre, 63);
  int base = 0;
  if (lane == 63) base = atomicAdd(counter, total);   // 1 atomic per wave
  base = __shfl(base, 63);
  int start = base + pre - d;
  if (v < N) { off[v] = start; cursor[v] = start; }
}

__global__ void k_scatter(const int* __restrict__ src, const int* __restrict__ dst,
                          int* __restrict__ cursor, int* __restrict__ csr_src,
                          int* __restrict__ csr_eid, int E) {
  int e = blockIdx.x * blockDim.x + threadIdx.x;
  if (e < E) {
    int d = dst[e];
    int p = atomicAdd(&cursor[d], 1);
    csr_src[p] = src[e];
    csr_eid[p] = e;
  }
}

// acc16[v][j] = sum over in-edges e of edge_feat[e][j]   (16 lanes per node)
__global__ void k_acc16(const float* __restrict__ edge_feat, const int* __restrict__ off,
                        const int* __restrict__ deg, const int* __restrict__ csr_eid,
                        float* __restrict__ acc16, int N) {
  int g = threadIdx.x >> 4;
  int j = threadIdx.x & 15;
  int v = blockIdx.x * 16 + g;
  if (v >= N) return;
  int o = off[v], d = deg[v];
  float a = 0.f;
  for (int i = 0; i < d; ++i) {
    int e = csr_eid[o + i];
    a += edge_feat[(size_t)e * 16 + j];
  }
  acc16[(size_t)v * 16 + j] = a;
}

// ---------------- GEMM: C[nrows,128] = A[nrows,128] @ W[128,128] (+extras) ----
// MODE 0: n2l  : v = A@W + b_n2l + acc16@w_e2l + deg*b_e2l ; IM=v ; C=relu(v)
// MODE 1: conv : C = A@W
// MODE 2: out  : C = relu(A@W + bias)
template<int MODE>
__global__ __launch_bounds__(256) void k_gemm(
    const float* __restrict__ A, const float* __restrict__ W,
    const float* __restrict__ bias,
    const float* __restrict__ A2, const float* __restrict__ W2,
    const float* __restrict__ bias2, const int* __restrict__ deg,
    float* __restrict__ C, float* __restrict__ IM, int nrows)
{
  __shared__ float At[KH][BR + 4];   // transposed A tile, pad 4 keeps 16B align
  __shared__ float Wl[KH][BC];
  int t = threadIdx.x;
  int r0 = blockIdx.x * BR;
  int c0 = blockIdx.y * BC;
  int tx = t & 15, ty = t >> 4;      // 4x4 micro-tile per thread
  float acc[4][4] = {};

  for (int kb = 0; kb < 128; kb += KH) {
    __syncthreads();
    #pragma unroll
    for (int i = 0; i < (BR * KH) / 256; ++i) {
      int idx = i * 256 + t;
      int r = idx >> 6, k = idx & 63;
      float v = (r0 + r < nrows) ? A[(size_t)(r0 + r) * 128 + kb + k] : 0.f;
      At[k][r] = v;
    }
    #pragma unroll
    for (int i = 0; i < (KH * BC) / 256; ++i) {
      int idx = i * 256 + t;
      int k = idx >> 6, c = idx & 63;
      Wl[k][c] = W[(size_t)(kb + k) * 128 + c0 + c];
    }
    __syncthreads();
    #pragma unroll
    for (int k = 0; k < KH; ++k) {
      float4 a = *(const float4*)&At[k][ty * 4];
      float4 w = *(const float4*)&Wl[k][tx * 4];
      float av[4] = {a.x, a.y, a.z, a.w};
      float wv[4] = {w.x, w.y, w.z, w.w};
      #pragma unroll
      for (int i = 0; i < 4; ++i)
        #pragma unroll
        for (int j = 0; j < 4; ++j)
          acc[i][j] += av[i] * wv[j];
    }
  }

  if (MODE == 0) {  // fold in acc16 @ w_e2l (K=16) straight from global (L2-hot)
    #pragma unroll
    for (int k2 = 0; k2 < 16; ++k2) {
      float4 w2 = *(const float4*)&W2[(size_t)k2 * 128 + c0 + tx * 4];
      float wv[4] = {w2.x, w2.y, w2.z, w2.w};
      #pragma unroll
      for (int i = 0; i < 4; ++i) {
        int r = r0 + ty * 4 + i;
        float a2 = (r < nrows) ? A2[(size_t)r * 16 + k2] : 0.f;
        #pragma unroll
        for (int j = 0; j < 4; ++j) acc[i][j] += a2 * wv[j];
      }
    }
  }

  #pragma unroll
  for (int i = 0; i < 4; ++i) {
    int r = r0 + ty * 4 + i;
    if (r < nrows) {
      size_t base = (size_t)r * 128 + c0 + tx * 4;
      #pragma unroll
      for (int j = 0; j < 4; ++j) {
        int c = c0 + tx * 4 + j;
        float v = acc[i][j];
        if (MODE == 0) {
          v += bias[c] + (float)deg[r] * bias2[c];
          IM[base + j] = v;
          C[base + j] = fmaxf(v, 0.f);
        } else if (MODE == 1) {
          C[base + j] = v;
        } else {
          v += bias[c];
          C[base + j] = fmaxf(v, 0.f);
        }
      }
    }
  }
}

// ------------- pool+update: h[v] = relu(sum_in hw[src] + b_conv + im[v]) -----
__global__ void k_pool_update(const float* __restrict__ hw, const int* __restrict__ off,
                              const int* __restrict__ deg, const int* __restrict__ csr_src,
                              const float* __restrict__ bconv, const float* __restrict__ im,
                              float* __restrict__ h, int N) {
  int wid = (int)((blockIdx.x * (size_t)blockDim.x + threadIdx.x) >> 6);  // one wave per node
  int lane = threadIdx.x & 63;
  if (wid >= N) return;
  int o = off[wid], d = deg[wid];
  float ax = 0.f, ay = 0.f;
  for (int i = 0; i < d; ++i) {
    int s = csr_src[o + i];
    float2 v = ((const float2*)(hw + (size_t)s * 128))[lane];
    ax += v.x; ay += v.y;
  }
  float2 b = ((const float2*)bconv)[lane];
  float2 m = ((const float2*)(im + (size_t)wid * 128))[lane];
  float2 r;
  r.x = fmaxf(ax + b.x + m.x, 0.f);
  r.y = fmaxf(ay + b.y + m.y, 0.f);
  ((float2*)(h + (size_t)wid * 128))[lane] = r;
}

// ------------- graph pooling: y[g] = relu(sum_{rows of g} act[row]) ----------
__global__ void k_graphpool(const float* __restrict__ act, const int* __restrict__ gid,
                            float* __restrict__ out, int N) {
  __shared__ int s_lo, s_hi;
  __shared__ float red[8][32];
  int g = blockIdx.x;
  int chunk = blockIdx.y;
  int t = threadIdx.x;
  if (t == 0) {
    int lo = 0, hi = N;
    while (lo < hi) { int mid = (lo + hi) >> 1; if (gid[mid] < g) lo = mid + 1; else hi = mid; }
    s_lo = lo;
    lo = 0; hi = N;
    while (lo < hi) { int mid = (lo + hi) >> 1; if (gid[mid] < g + 1) lo = mid + 1; else hi = mid; }
    s_hi = lo;
  }
  __syncthreads();
  int c = chunk * 32 + (t & 31);
  int rid = t >> 5;
  float acc = 0.f;
  for (int r = s_lo + rid; r < s_hi; r += 8)
    acc += act[(size_t)r * 128 + c];
  red[rid][t & 31] = acc;
  __syncthreads();
  if (rid == 0) {
    float s = 0.f;
    #pragma unroll
    for (int i = 0; i < 8; ++i) s += red[i][t & 31];
    out[(size_t)g * 128 + (t & 31) + chunk * 32] = fmaxf(s, 0.f);
  }
}

extern "C" void kernel_launch(void* const* d_in, const int* in_sizes, int n_in,
                              void* d_out, int out_size, void* d_ws, size_t ws_size,
                              hipStream_t stream) {
  const float* node_feat = (const float*)d_in[0];
  const float* edge_feat = (const float*)d_in[1];
  const int*   edge_src  = (const int*)d_in[2];
  const int*   edge_dst  = (const int*)d_in[3];
  const int*   graph_ids = (const int*)d_in[4];
  const float* w_n2l = (const float*)d_in[5];
  const float* b_n2l = (const float*)d_in[6];
  const float* w_e2l = (const float*)d_in[7];
  const float* b_e2l = (const float*)d_in[8];
  const float* w_conv = (const float*)d_in[9];
  const float* b_conv = (const float*)d_in[10];
  const float* w_out  = (const float*)d_in[11];
  const float* b_out  = (const float*)d_in[12];

  int N = in_sizes[0] / 128;
  int E = in_sizes[2];

  // workspace layout (~174 MB)
  float* im    = (float*)d_ws;
  float* h     = im + (size_t)N * 128;
  float* hw    = h  + (size_t)N * 128;
  float* acc16 = hw + (size_t)N * 128;
  int* deg     = (int*)(acc16 + (size_t)N * 16);
  int* off     = deg + N;
  int* cursor  = off + N;
  int* csr_src = cursor + N;
  int* csr_eid = csr_src + E;
  int* counter = csr_eid + E;

  hipMemsetAsync(deg, 0, (size_t)N * sizeof(int), stream);
  hipMemsetAsync(counter, 0, sizeof(int), stream);

  int eb = (E + 255) / 256;
  k_hist<<<eb, 256, 0, stream>>>(edge_dst, deg, E);
  k_alloc<<<(N + 255) / 256, 256, 0, stream>>>(deg, off, cursor, counter, N);
  k_scatter<<<eb, 256, 0, stream>>>(edge_src, edge_dst, cursor, csr_src, csr_eid, E);
  k_acc16<<<(N + 15) / 16, 256, 0, stream>>>(edge_feat, off, deg, csr_eid, acc16, N);

  dim3 gg((N + BR - 1) / BR, 128 / BC);
  k_gemm<0><<<gg, 256, 0, stream>>>(node_feat, w_n2l, b_n2l, acc16, w_e2l, b_e2l, deg, h, im, N);
  for (int it = 0; it < 3; ++it) {
    k_gemm<1><<<gg, 256, 0, stream>>>(h, w_conv, nullptr, nullptr, nullptr, nullptr, nullptr, hw, nullptr, N);
    k_pool_update<<<((size_t)N * 64 + 255) / 256, 256, 0, stream>>>(hw, off, deg, csr_src, b_conv, im, h, N);
  }
  k_gemm<2><<<gg, 256, 0, stream>>>(h, w_out, b_out, nullptr, nullptr, nullptr, nullptr, hw, nullptr, N);

  dim3 gp(out_size / 128, 4);
  k_graphpool<<<gp, 256, 0, stream>>>(hw, graph_ids, (float*)d_out, N);
}

// Round 3
// 1174.402 us; speedup vs baseline: 1.3966x; 1.3966x over previous
//
#include <hip/hip_runtime.h>

typedef unsigned int uint;
typedef unsigned short ushort;
typedef __bf16 bf16x8 __attribute__((ext_vector_type(8)));
typedef float f32x4 __attribute__((ext_vector_type(4)));

__device__ __forceinline__ ushort f2b(float f) {           // f32 -> bf16 RNE
  uint u = __builtin_bit_cast(uint, f);
  u += 0x7fffu + ((u >> 16) & 1u);
  return (ushort)(u >> 16);
}
__device__ __forceinline__ float b2f(ushort s) {
  uint u = (uint)s << 16;
  return __builtin_bit_cast(float, u);
}

// ---------------- CSR build ----------------
__global__ void k_hist(const int* __restrict__ dst, int* __restrict__ deg, int E) {
  int e = blockIdx.x * blockDim.x + threadIdx.x;
  if (e < E) atomicAdd(&deg[dst[e]], 1);
}

__global__ void k_alloc(const int* __restrict__ deg, int* __restrict__ off,
                        int* __restrict__ cursor, int* __restrict__ counter, int N) {
  int v = blockIdx.x * blockDim.x + threadIdx.x;
  int lane = threadIdx.x & 63;
  int d = (v < N) ? deg[v] : 0;
  int pre = d;
  #pragma unroll
  for (int s = 1; s < 64; s <<= 1) {
    int t = __shfl_up(pre, s);
    if (lane >= s) pre += t;
  }
  int total = __shfl(pre, 63);
  int base = 0;
  if (lane == 63) base = atomicAdd(counter, total);   // 1 atomic per wave
  base = __shfl(base, 63);
  int start = base + pre - d;
  if (v < N) { off[v] = start; cursor[v] = start; }
}

__global__ void k_scatter(const int* __restrict__ src, const int* __restrict__ dst,
                          int* __restrict__ cursor, int* __restrict__ csr_src,
                          int* __restrict__ csr_eid, int E) {
  int e = blockIdx.x * blockDim.x + threadIdx.x;
  if (e < E) {
    int d = dst[e];
    int p = atomicAdd(&cursor[d], 1);
    csr_src[p] = src[e];
    csr_eid[p] = e;
  }
}

// Ab[v][128+j] = bf16( sum_in-edges edge_feat[e][j] )  (j<16), deg at col 144, 0 pad to 160
__global__ void k_acc16b(const float* __restrict__ edge_feat, const int* __restrict__ off,
                         const int* __restrict__ deg, const int* __restrict__ csr_eid,
                         ushort* __restrict__ Ab, int N) {
  int g = threadIdx.x >> 5;     // 8 nodes per 256-thread block, 32 lanes each
  int j = threadIdx.x & 31;
  int v = blockIdx.x * 8 + g;
  if (v >= N) return;
  int o = off[v], d = deg[v];
  float a = 0.f;
  if (j < 16) {
    for (int i = 0; i < d; ++i) {
      int e = csr_eid[o + i];
      a += edge_feat[(size_t)e * 16 + j];
    }
  } else if (j == 16) {
    a = (float)d;
  }
  Ab[(size_t)v * 160 + 128 + j] = f2b(a);
}

// Ab[row][0..127] = bf16(node_feat[row]); pad rows -> all-zero
__global__ void k_convA(const float* __restrict__ nf, ushort* __restrict__ Ab, int N, int Mpad) {
  size_t row = (blockIdx.x * (size_t)blockDim.x + threadIdx.x) >> 6;
  int l = threadIdx.x & 63;
  if (row >= (size_t)Mpad) return;
  if (row < (size_t)N) {
    float2 v = *(const float2*)(nf + row * 128 + l * 2);
    uint o = (uint)f2b(v.x) | ((uint)f2b(v.y) << 16);
    *(uint*)(Ab + row * 160 + l * 2) = o;
  } else {
    *(uint*)(Ab + row * 160 + l * 2) = 0u;
    if (l < 16) *(uint*)(Ab + row * 160 + 128 + l * 2) = 0u;
  }
}

// transposed bf16 weights: Wtn[c][k] (K=160: w_n2l ; w_e2l ; b_e2l ; 0), Wtc/Wto[c][k] (K=128)
__global__ void k_wt(const float* __restrict__ w_n2l, const float* __restrict__ w_e2l,
                     const float* __restrict__ b_e2l, const float* __restrict__ w_conv,
                     const float* __restrict__ w_out,
                     ushort* __restrict__ Wtn, ushort* __restrict__ Wtc, ushort* __restrict__ Wto) {
  int c = blockIdx.x;     // 0..127 (output col)
  int k = threadIdx.x;
  int s = blockIdx.y;
  if (s == 0) {
    if (k < 160) {
      float v = (k < 128) ? w_n2l[(size_t)k * 128 + c]
              : (k < 144) ? w_e2l[(size_t)(k - 128) * 128 + c]
              : (k == 144) ? b_e2l[c] : 0.f;
      Wtn[(size_t)c * 160 + k] = f2b(v);
    }
  } else if (s == 1) {
    if (k < 128) Wtc[(size_t)c * 128 + k] = f2b(w_conv[(size_t)k * 128 + c]);
  } else {
    if (k < 128) Wto[(size_t)c * 128 + k] = f2b(w_out[(size_t)k * 128 + c]);
  }
}

// ---------------- MFMA GEMM: C[Mpad,128] = A[Mpad,KA] @ Wt^T, no LDS ----------------
// MODE 0 (n2l): v = sum + bias;  C = relu(v) bf16;  C2 = bf16(v + bias2)   [bias2=b_conv]
// MODE 1 (conv): C = bf16(sum)
// MODE 2 (out) : C = relu(sum + bias) bf16
// Wave computes 32 rows x 128 cols. A-frag: lane holds A[row0+16tr+(l&15)][32ks+8(l>>4)+j].
// B-frag: lane holds W[k][tc*16+(l&15)] = Wt[col][k], same addressing as A.
// D layout (m89-verified): col = l&15, row = 4*(l>>4)+reg.
template<int KSTEPS, int MODE>
__global__ __launch_bounds__(256) void k_mm(
    const ushort* __restrict__ A, const ushort* __restrict__ Wt,
    const float* __restrict__ bias, const float* __restrict__ bias2,
    ushort* __restrict__ C, ushort* __restrict__ C2) {
  const int KA = KSTEPS * 32;
  int l = threadIdx.x & 63;
  int w = threadIdx.x >> 6;
  int lr = l & 15, lg = l >> 4;
  size_t row0 = (size_t)blockIdx.x * 128 + (size_t)w * 32;

  bf16x8 a[2][KSTEPS];
  #pragma unroll
  for (int tr = 0; tr < 2; ++tr) {
    const ushort* p = A + (row0 + tr * 16 + lr) * KA + lg * 8;
    #pragma unroll
    for (int ks = 0; ks < KSTEPS; ++ks)
      a[tr][ks] = *(const bf16x8*)(const void*)(p + ks * 32);
  }

  f32x4 acc[2][8];
  #pragma unroll
  for (int tr = 0; tr < 2; ++tr)
    #pragma unroll
    for (int tc = 0; tc < 8; ++tc)
      acc[tr][tc] = (f32x4){0.f, 0.f, 0.f, 0.f};

  #pragma unroll
  for (int tc = 0; tc < 8; ++tc) {
    const ushort* p = Wt + (size_t)(tc * 16 + lr) * KA + lg * 8;
    bf16x8 b[KSTEPS];
    #pragma unroll
    for (int ks = 0; ks < KSTEPS; ++ks)
      b[ks] = *(const bf16x8*)(const void*)(p + ks * 32);
    #pragma unroll
    for (int ks = 0; ks < KSTEPS; ++ks) {
      acc[0][tc] = __builtin_amdgcn_mfma_f32_16x16x32_bf16(a[0][ks], b[ks], acc[0][tc], 0, 0, 0);
      acc[1][tc] = __builtin_amdgcn_mfma_f32_16x16x32_bf16(a[1][ks], b[ks], acc[1][tc], 0, 0, 0);
    }
  }

  #pragma unroll
  for (int tc = 0; tc < 8; ++tc) {
    int col = tc * 16 + lr;
    float bv = (MODE != 1) ? bias[col] : 0.f;
    float b2v = (MODE == 0) ? bias2[col] : 0.f;
    #pragma unroll
    for (int tr = 0; tr < 2; ++tr) {
      size_t rbase = row0 + tr * 16 + lg * 4;
      #pragma unroll
      for (int e = 0; e < 4; ++e) {
        float v = acc[tr][tc][e];
        size_t idx = (rbase + e) * 128 + col;
        if (MODE == 0) {
          v += bv;
          C[idx] = f2b(fmaxf(v, 0.f));
          C2[idx] = f2b(v + b2v);
        } else if (MODE == 1) {
          C[idx] = f2b(v);
        } else {
          C[idx] = f2b(fmaxf(v + bv, 0.f));
        }
      }
    }
  }
}

// ------------- pool+update: hb[v] = relu(sum_in hwb[src] + im2b[v]) (all bf16, f32 accum) ----
__global__ void k_pool_b(const ushort* __restrict__ hwb, const int* __restrict__ off,
                         const int* __restrict__ deg, const int* __restrict__ csr_src,
                         const ushort* __restrict__ im2b, ushort* __restrict__ hb, int N) {
  int wid = (int)((blockIdx.x * (size_t)blockDim.x + threadIdx.x) >> 6);  // one wave per node
  int l = threadIdx.x & 63;
  if (wid >= N) return;
  int o = off[wid], d = deg[wid];
  float ax = 0.f, ay = 0.f;
  for (int i = 0; i < d; ++i) {
    int s = csr_src[o + i];
    uint u = *(const uint*)(hwb + (size_t)s * 128 + l * 2);
    ax += __builtin_bit_cast(float, u << 16);
    ay += __builtin_bit_cast(float, u & 0xffff0000u);
  }
  uint m = *(const uint*)(im2b + (size_t)wid * 128 + l * 2);
  float rx = fmaxf(ax + __builtin_bit_cast(float, m << 16), 0.f);
  float ry = fmaxf(ay + __builtin_bit_cast(float, m & 0xffff0000u), 0.f);
  uint out = (uint)f2b(rx) | ((uint)f2b(ry) << 16);
  *(uint*)(hb + (size_t)wid * 128 + l * 2) = out;
}

// ------------- graph pooling: y[g] = relu(sum_{rows of g} actb[row]) ----------
__global__ void k_graphpool_b(const ushort* __restrict__ act, const int* __restrict__ gid,
                              float* __restrict__ out, int N) {
  __shared__ int s_lo, s_hi;
  __shared__ float red[8][32];
  int g = blockIdx.x;
  int chunk = blockIdx.y;
  int t = threadIdx.x;
  if (t == 0) {
    int lo = 0, hi = N;
    while (lo < hi) { int mid = (lo + hi) >> 1; if (gid[mid] < g) lo = mid + 1; else hi = mid; }
    s_lo = lo;
    lo = 0; hi = N;
    while (lo < hi) { int mid = (lo + hi) >> 1; if (gid[mid] < g + 1) lo = mid + 1; else hi = mid; }
    s_hi = lo;
  }
  __syncthreads();
  int c = chunk * 32 + (t & 31);
  int rid = t >> 5;
  float acc = 0.f;
  for (int r = s_lo + rid; r < s_hi; r += 8)
    acc += b2f(act[(size_t)r * 128 + c]);
  red[rid][t & 31] = acc;
  __syncthreads();
  if (rid == 0) {
    float s = 0.f;
    #pragma unroll
    for (int i = 0; i < 8; ++i) s += red[i][t & 31];
    out[(size_t)g * 128 + c] = fmaxf(s, 0.f);
  }
}

extern "C" void kernel_launch(void* const* d_in, const int* in_sizes, int n_in,
                              void* d_out, int out_size, void* d_ws, size_t ws_size,
                              hipStream_t stream) {
  const float* node_feat = (const float*)d_in[0];
  const float* edge_feat = (const float*)d_in[1];
  const int*   edge_src  = (const int*)d_in[2];
  const int*   edge_dst  = (const int*)d_in[3];
  const int*   graph_ids = (const int*)d_in[4];
  const float* w_n2l  = (const float*)d_in[5];
  const float* b_n2l  = (const float*)d_in[6];
  const float* w_e2l  = (const float*)d_in[7];
  const float* b_e2l  = (const float*)d_in[8];
  const float* w_conv = (const float*)d_in[9];
  const float* b_conv = (const float*)d_in[10];
  const float* w_out  = (const float*)d_in[11];
  const float* b_out  = (const float*)d_in[12];

  int N = in_sizes[0] / 128;
  int E = in_sizes[2];
  int Mpad = ((N + 127) / 128) * 128;

  // ---- workspace carve (~149 MB) ----
  ushort* Ab   = (ushort*)d_ws;                     // [Mpad][160]
  ushort* hb   = Ab   + (size_t)Mpad * 160;         // [Mpad][128]
  ushort* hwb  = hb   + (size_t)Mpad * 128;
  ushort* im2b = hwb  + (size_t)Mpad * 128;
  ushort* actb = im2b + (size_t)Mpad * 128;
  ushort* Wtn  = actb + (size_t)Mpad * 128;         // [128][160]
  ushort* Wtc  = Wtn + 128 * 160;                   // [128][128]
  ushort* Wto  = Wtc + 128 * 128;
  int* deg     = (int*)(Wto + 128 * 128);
  int* off     = deg + N;
  int* cursor  = off + N;
  int* csr_src = cursor + N;
  int* csr_eid = csr_src + E;
  int* counter = csr_eid + E;

  hipMemsetAsync(deg, 0, (size_t)N * sizeof(int), stream);
  hipMemsetAsync(counter, 0, sizeof(int), stream);

  int eb = (E + 255) / 256;
  k_hist<<<eb, 256, 0, stream>>>(edge_dst, deg, E);
  k_alloc<<<(N + 255) / 256, 256, 0, stream>>>(deg, off, cursor, counter, N);
  k_scatter<<<eb, 256, 0, stream>>>(edge_src, edge_dst, cursor, csr_src, csr_eid, E);
  k_acc16b<<<(N + 7) / 8, 256, 0, stream>>>(edge_feat, off, deg, csr_eid, Ab, N);
  k_convA<<<Mpad / 4, 256, 0, stream>>>(node_feat, Ab, N, Mpad);
  k_wt<<<dim3(128, 3), 256, 0, stream>>>(w_n2l, w_e2l, b_e2l, w_conv, w_out, Wtn, Wtc, Wto);

  int gB = Mpad / 128;
  k_mm<5, 0><<<gB, 256, 0, stream>>>(Ab, Wtn, b_n2l, b_conv, hb, im2b);
  for (int it = 0; it < 3; ++it) {
    k_mm<4, 1><<<gB, 256, 0, stream>>>(hb, Wtc, nullptr, nullptr, hwb, nullptr);
    k_pool_b<<<((size_t)N * 64 + 255) / 256, 256, 0, stream>>>(hwb, off, deg, csr_src, im2b, hb, N);
  }
  k_mm<4, 2><<<gB, 256, 0, stream>>>(hb, Wto, b_out, nullptr, actb, nullptr);

  dim3 gp(out_size / 128, 4);
  k_graphpool_b<<<gp, 256, 0, stream>>>(actb, graph_ids, (float*)d_out, N);
}

// Round 4
// 847.075 us; speedup vs baseline: 1.9363x; 1.3864x over previous
//
#include <hip/hip_runtime.h>

typedef unsigned int uint;
typedef unsigned short ushort;
typedef __bf16 bf16x8 __attribute__((ext_vector_type(8)));
typedef float f32x4 __attribute__((ext_vector_type(4)));

__device__ __forceinline__ ushort f2b(float f) {           // f32 -> bf16 RNE
  uint u = __builtin_bit_cast(uint, f);
  u += 0x7fffu + ((u >> 16) & 1u);
  return (ushort)(u >> 16);
}
__device__ __forceinline__ float b2f(ushort s) {
  uint u = (uint)s << 16;
  return __builtin_bit_cast(float, u);
}
__device__ __forceinline__ float blo(uint u) { return __builtin_bit_cast(float, u << 16); }
__device__ __forceinline__ float bhi(uint u) { return __builtin_bit_cast(float, u & 0xffff0000u); }

// ---------------- CSR build ----------------
__global__ void k_hist(const int* __restrict__ dst, int* __restrict__ deg, int E) {
  int e = blockIdx.x * blockDim.x + threadIdx.x;
  if (e < E) atomicAdd(&deg[dst[e]], 1);
}

// prefill padded CSR arrays: src -> N (zero-row sentinel), eid -> -1 (pad marker)
__global__ void k_fill(int* __restrict__ csr_src, int* __restrict__ csr_eid, int cap, int N) {
  int i = blockIdx.x * blockDim.x + threadIdx.x;
  if (i < cap) { csr_src[i] = N; csr_eid[i] = -1; }
}

// per-node slot count padded to multiple of 8 (branch-free pooled gather)
__global__ void k_alloc(const int* __restrict__ deg, int* __restrict__ off,
                        int* __restrict__ cursor, int* __restrict__ counter, int N) {
  int v = blockIdx.x * blockDim.x + threadIdx.x;
  int lane = threadIdx.x & 63;
  int d = (v < N) ? ((deg[v] + 7) & ~7) : 0;
  int pre = d;
  #pragma unroll
  for (int s = 1; s < 64; s <<= 1) {
    int t = __shfl_up(pre, s);
    if (lane >= s) pre += t;
  }
  int total = __shfl(pre, 63);
  int base = 0;
  if (lane == 63) base = atomicAdd(counter, total);   // 1 atomic per wave
  base = __shfl(base, 63);
  int start = base + pre - d;
  if (v < N) { off[v] = start; cursor[v] = start; }
}

__global__ void k_scatter(const int* __restrict__ src, const int* __restrict__ dst,
                          int* __restrict__ cursor, int* __restrict__ csr_src,
                          int* __restrict__ csr_eid, int E) {
  int e = blockIdx.x * blockDim.x + threadIdx.x;
  if (e < E) {
    int d = dst[e];
    int p = atomicAdd(&cursor[d], 1);
    csr_src[p] = src[e];
    csr_eid[p] = e;
  }
}

// edge-parallel: sorted_ef[p] = bf16(edge_feat[csr_eid[p]]) (32B rows), zeros for pads
__global__ void k_sortef(const float* __restrict__ ef, const int* __restrict__ csr_eid,
                         ushort* __restrict__ sorted, int cap) {
  int p = blockIdx.x * blockDim.x + threadIdx.x;
  if (p >= cap) return;
  int e = csr_eid[p];
  uint4 o0 = {0u, 0u, 0u, 0u}, o1 = {0u, 0u, 0u, 0u};
  if (e >= 0) {
    const float4* f = (const float4*)(ef + (size_t)e * 16);
    float4 a = f[0], b = f[1], c = f[2], d4 = f[3];
    o0.x = (uint)f2b(a.x) | ((uint)f2b(a.y) << 16);
    o0.y = (uint)f2b(a.z) | ((uint)f2b(a.w) << 16);
    o0.z = (uint)f2b(b.x) | ((uint)f2b(b.y) << 16);
    o0.w = (uint)f2b(b.z) | ((uint)f2b(b.w) << 16);
    o1.x = (uint)f2b(c.x) | ((uint)f2b(c.y) << 16);
    o1.y = (uint)f2b(c.z) | ((uint)f2b(c.w) << 16);
    o1.z = (uint)f2b(d4.x) | ((uint)f2b(d4.y) << 16);
    o1.w = (uint)f2b(d4.z) | ((uint)f2b(d4.w) << 16);
  }
  uint4* op = (uint4*)(sorted + (size_t)p * 16);
  op[0] = o0; op[1] = o1;
}

// streaming per-node sum of sorted_ef rows -> Ab cols 128..159 (wave per node)
// lane = i_sub*8 + jj : i_sub = 8 rows/iter, jj = col pair
__global__ void k_acc16s(const ushort* __restrict__ sorted, const int* __restrict__ off,
                         const int* __restrict__ deg, ushort* __restrict__ Ab, int N) {
  int wid = (int)((blockIdx.x * (size_t)blockDim.x + threadIdx.x) >> 6);
  int l = threadIdx.x & 63;
  if (wid >= N) return;
  int o = off[wid];
  int d = deg[wid];
  int dp = (d + 7) & ~7;
  int i_sub = l >> 3, jj = l & 7;
  float ax = 0.f, ay = 0.f;
  for (int base = 0; base < dp; base += 8) {
    uint u = *(const uint*)(sorted + (size_t)(o + base + i_sub) * 16 + jj * 2);
    ax += blo(u); ay += bhi(u);
  }
  ax += __shfl_xor(ax, 8);  ay += __shfl_xor(ay, 8);
  ax += __shfl_xor(ax, 16); ay += __shfl_xor(ay, 16);
  ax += __shfl_xor(ax, 32); ay += __shfl_xor(ay, 32);
  if (l < 16) {
    uint out;
    if (l < 8)       out = (uint)f2b(ax) | ((uint)f2b(ay) << 16);
    else if (l == 8) out = (uint)f2b((float)d);            // (deg, 0)
    else             out = 0u;                             // zero pad cols
    *(uint*)(Ab + (size_t)wid * 160 + 128 + l * 2) = out;
  }
}

// Ab[row][0..127] = bf16(node_feat[row]); pad rows -> all-zero
__global__ void k_convA(const float* __restrict__ nf, ushort* __restrict__ Ab, int N, int Mpad) {
  size_t row = (blockIdx.x * (size_t)blockDim.x + threadIdx.x) >> 6;
  int l = threadIdx.x & 63;
  if (row >= (size_t)Mpad) return;
  if (row < (size_t)N) {
    float2 v = *(const float2*)(nf + row * 128 + l * 2);
    uint o = (uint)f2b(v.x) | ((uint)f2b(v.y) << 16);
    *(uint*)(Ab + row * 160 + l * 2) = o;
  } else {
    *(uint*)(Ab + row * 160 + l * 2) = 0u;
    if (l < 16) *(uint*)(Ab + row * 160 + 128 + l * 2) = 0u;
  }
}

// transposed bf16 weights: Wtn[c][k] (K=160: w_n2l ; w_e2l ; b_e2l ; 0), Wtc/Wto[c][k] (K=128)
__global__ void k_wt(const float* __restrict__ w_n2l, const float* __restrict__ w_e2l,
                     const float* __restrict__ b_e2l, const float* __restrict__ w_conv,
                     const float* __restrict__ w_out,
                     ushort* __restrict__ Wtn, ushort* __restrict__ Wtc, ushort* __restrict__ Wto) {
  int c = blockIdx.x;     // 0..127 (output col)
  int k = threadIdx.x;
  int s = blockIdx.y;
  if (s == 0) {
    if (k < 160) {
      float v = (k < 128) ? w_n2l[(size_t)k * 128 + c]
              : (k < 144) ? w_e2l[(size_t)(k - 128) * 128 + c]
              : (k == 144) ? b_e2l[c] : 0.f;
      Wtn[(size_t)c * 160 + k] = f2b(v);
    }
  } else if (s == 1) {
    if (k < 128) Wtc[(size_t)c * 128 + k] = f2b(w_conv[(size_t)k * 128 + c]);
  } else {
    if (k < 128) Wto[(size_t)c * 128 + k] = f2b(w_out[(size_t)k * 128 + c]);
  }
}

// ---------------- MFMA GEMM: C[Mpad,128] = A[Mpad,KA] @ Wt^T, no LDS ----------------
// MODE 0 (n2l): v = sum + bias;  C = relu(v) bf16;  C2 = bf16(v + bias2); rows>=nrows -> 0
// MODE 1 (conv): C = bf16(sum)
// MODE 2 (out) : C = relu(sum + bias) bf16
template<int KSTEPS, int MODE>
__global__ __launch_bounds__(256) void k_mm(
    const ushort* __restrict__ A, const ushort* __restrict__ Wt,
    const float* __restrict__ bias, const float* __restrict__ bias2,
    ushort* __restrict__ C, ushort* __restrict__ C2, int nrows) {
  const int KA = KSTEPS * 32;
  int l = threadIdx.x & 63;
  int w = threadIdx.x >> 6;
  int lr = l & 15, lg = l >> 4;
  size_t row0 = (size_t)blockIdx.x * 128 + (size_t)w * 32;

  bf16x8 a[2][KSTEPS];
  #pragma unroll
  for (int tr = 0; tr < 2; ++tr) {
    const ushort* p = A + (row0 + tr * 16 + lr) * KA + lg * 8;
    #pragma unroll
    for (int ks = 0; ks < KSTEPS; ++ks)
      a[tr][ks] = *(const bf16x8*)(const void*)(p + ks * 32);
  }

  f32x4 acc[2][8];
  #pragma unroll
  for (int tr = 0; tr < 2; ++tr)
    #pragma unroll
    for (int tc = 0; tc < 8; ++tc)
      acc[tr][tc] = (f32x4){0.f, 0.f, 0.f, 0.f};

  #pragma unroll
  for (int tc = 0; tc < 8; ++tc) {
    const ushort* p = Wt + (size_t)(tc * 16 + lr) * KA + lg * 8;
    bf16x8 b[KSTEPS];
    #pragma unroll
    for (int ks = 0; ks < KSTEPS; ++ks)
      b[ks] = *(const bf16x8*)(const void*)(p + ks * 32);
    #pragma unroll
    for (int ks = 0; ks < KSTEPS; ++ks) {
      acc[0][tc] = __builtin_amdgcn_mfma_f32_16x16x32_bf16(a[0][ks], b[ks], acc[0][tc], 0, 0, 0);
      acc[1][tc] = __builtin_amdgcn_mfma_f32_16x16x32_bf16(a[1][ks], b[ks], acc[1][tc], 0, 0, 0);
    }
  }

  #pragma unroll
  for (int tc = 0; tc < 8; ++tc) {
    int col = tc * 16 + lr;
    float bv = (MODE != 1) ? bias[col] : 0.f;
    float b2v = (MODE == 0) ? bias2[col] : 0.f;
    #pragma unroll
    for (int tr = 0; tr < 2; ++tr) {
      size_t rbase = row0 + tr * 16 + lg * 4;
      #pragma unroll
      for (int e = 0; e < 4; ++e) {
        float v = acc[tr][tc][e];
        size_t r = rbase + e;
        size_t idx = r * 128 + col;
        if (MODE == 0) {
          if (r < (size_t)nrows) {
            float vb = v + bv;
            C[idx] = f2b(fmaxf(vb, 0.f));
            C2[idx] = f2b(vb + b2v);
          } else {
            C[idx] = 0; C2[idx] = 0;       // keep pad rows exactly zero (row N is pool sentinel)
          }
        } else if (MODE == 1) {
          C[idx] = f2b(v);
        } else {
          C[idx] = f2b(fmaxf(v + bv, 0.f));
        }
      }
    }
  }
}

// ------------- pool+update: hb[v] = relu(sum_in hwb[src] + im2b[v]) ----------
// padded CSR (multiple of 8, sentinel row N == zeros) -> branch-free 8-deep MLP
__global__ void k_pool_b(const ushort* __restrict__ hwb, const int* __restrict__ off,
                         const int* __restrict__ deg, const int* __restrict__ csr_src,
                         const ushort* __restrict__ im2b, ushort* __restrict__ hb, int N) {
  int wid = (int)((blockIdx.x * (size_t)blockDim.x + threadIdx.x) >> 6);  // one wave per node
  int l = threadIdx.x & 63;
  if (wid >= N) return;
  int o = off[wid];
  int dp = (deg[wid] + 7) & ~7;
  const uint* __restrict__ rows = (const uint*)hwb;
  float ax = 0.f, ay = 0.f;
  for (int i = 0; i < dp; i += 8) {
    int s0 = csr_src[o + i + 0], s1 = csr_src[o + i + 1];
    int s2 = csr_src[o + i + 2], s3 = csr_src[o + i + 3];
    int s4 = csr_src[o + i + 4], s5 = csr_src[o + i + 5];
    int s6 = csr_src[o + i + 6], s7 = csr_src[o + i + 7];
    uint u0 = rows[(size_t)s0 * 64 + l];
    uint u1 = rows[(size_t)s1 * 64 + l];
    uint u2 = rows[(size_t)s2 * 64 + l];
    uint u3 = rows[(size_t)s3 * 64 + l];
    uint u4 = rows[(size_t)s4 * 64 + l];
    uint u5 = rows[(size_t)s5 * 64 + l];
    uint u6 = rows[(size_t)s6 * 64 + l];
    uint u7 = rows[(size_t)s7 * 64 + l];
    ax += blo(u0) + blo(u1) + blo(u2) + blo(u3) + blo(u4) + blo(u5) + blo(u6) + blo(u7);
    ay += bhi(u0) + bhi(u1) + bhi(u2) + bhi(u3) + bhi(u4) + bhi(u5) + bhi(u6) + bhi(u7);
  }
  uint m = ((const uint*)im2b)[(size_t)wid * 64 + l];
  float rx = fmaxf(ax + blo(m), 0.f);
  float ry = fmaxf(ay + bhi(m), 0.f);
  ((uint*)hb)[(size_t)wid * 64 + l] = (uint)f2b(rx) | ((uint)f2b(ry) << 16);
}

// ------------- graph pooling: y[g] = relu(sum_{rows of g} actb[row]) ----------
__global__ void k_graphpool_b(const ushort* __restrict__ act, const int* __restrict__ gid,
                              float* __restrict__ out, int N) {
  __shared__ int s_lo, s_hi;
  __shared__ float red[8][32];
  int g = blockIdx.x;
  int chunk = blockIdx.y;
  int t = threadIdx.x;
  if (t == 0) {
    int lo = 0, hi = N;
    while (lo < hi) { int mid = (lo + hi) >> 1; if (gid[mid] < g) lo = mid + 1; else hi = mid; }
    s_lo = lo;
    lo = 0; hi = N;
    while (lo < hi) { int mid = (lo + hi) >> 1; if (gid[mid] < g + 1) lo = mid + 1; else hi = mid; }
    s_hi = lo;
  }
  __syncthreads();
  int c = chunk * 32 + (t & 31);
  int rid = t >> 5;
  float acc = 0.f;
  for (int r = s_lo + rid; r < s_hi; r += 8)
    acc += b2f(act[(size_t)r * 128 + c]);
  red[rid][t & 31] = acc;
  __syncthreads();
  if (rid == 0) {
    float s = 0.f;
    #pragma unroll
    for (int i = 0; i < 8; ++i) s += red[i][t & 31];
    out[(size_t)g * 128 + c] = fmaxf(s, 0.f);
  }
}

extern "C" void kernel_launch(void* const* d_in, const int* in_sizes, int n_in,
                              void* d_out, int out_size, void* d_ws, size_t ws_size,
                              hipStream_t stream) {
  const float* node_feat = (const float*)d_in[0];
  const float* edge_feat = (const float*)d_in[1];
  const int*   edge_src  = (const int*)d_in[2];
  const int*   edge_dst  = (const int*)d_in[3];
  const int*   graph_ids = (const int*)d_in[4];
  const float* w_n2l  = (const float*)d_in[5];
  const float* b_n2l  = (const float*)d_in[6];
  const float* w_e2l  = (const float*)d_in[7];
  const float* b_e2l  = (const float*)d_in[8];
  const float* w_conv = (const float*)d_in[9];
  const float* b_conv = (const float*)d_in[10];
  const float* w_out  = (const float*)d_in[11];
  const float* b_out  = (const float*)d_in[12];

  int N = in_sizes[0] / 128;
  int E = in_sizes[2];
  int Mpad = ((N + 127) / 128) * 128;
  int cap = E + 7 * N;           // padded CSR capacity upper bound

  // ---- workspace carve (~156 MB) ----
  ushort* Ab   = (ushort*)d_ws;                     // [Mpad][160]
  ushort* hb   = Ab   + (size_t)Mpad * 160;         // [Mpad][128]
  ushort* hwb  = hb   + (size_t)Mpad * 128;
  ushort* im2b = hwb  + (size_t)Mpad * 128;
  ushort* actb = im2b + (size_t)Mpad * 128;
  ushort* Wtn  = actb + (size_t)Mpad * 128;         // [128][160]
  ushort* Wtc  = Wtn + 128 * 160;                   // [128][128]
  ushort* Wto  = Wtc + 128 * 128;
  int* deg     = (int*)(Wto + 128 * 128);
  int* off     = deg + N;
  int* cursor  = off + N;
  int* csr_src = cursor + N;
  int* csr_eid = csr_src + cap;
  int* counter = csr_eid + cap;
  // sorted_ef [cap][16] bf16 (73.6MB) aliases hwb|im2b|actb (77.1MB): dead before
  // mm<4,1> writes hwb / mm<5,0> writes im2b (acc16s is its last reader).
  ushort* sorted_ef = hwb;

  hipMemsetAsync(deg, 0, (size_t)N * sizeof(int), stream);
  hipMemsetAsync(counter, 0, sizeof(int), stream);

  int eb = (E + 255) / 256;
  int cb = (cap + 255) / 256;
  k_hist<<<eb, 256, 0, stream>>>(edge_dst, deg, E);
  k_fill<<<cb, 256, 0, stream>>>(csr_src, csr_eid, cap, N);
  k_alloc<<<(N + 255) / 256, 256, 0, stream>>>(deg, off, cursor, counter, N);
  k_scatter<<<eb, 256, 0, stream>>>(edge_src, edge_dst, cursor, csr_src, csr_eid, E);
  k_sortef<<<cb, 256, 0, stream>>>(edge_feat, csr_eid, sorted_ef, cap);
  k_acc16s<<<(N + 3) / 4, 256, 0, stream>>>(sorted_ef, off, deg, Ab, N);
  k_convA<<<Mpad / 4, 256, 0, stream>>>(node_feat, Ab, N, Mpad);
  k_wt<<<dim3(128, 3), 256, 0, stream>>>(w_n2l, w_e2l, b_e2l, w_conv, w_out, Wtn, Wtc, Wto);

  int gB = Mpad / 128;
  k_mm<5, 0><<<gB, 256, 0, stream>>>(Ab, Wtn, b_n2l, b_conv, hb, im2b, N);
  for (int it = 0; it < 3; ++it) {
    k_mm<4, 1><<<gB, 256, 0, stream>>>(hb, Wtc, nullptr, nullptr, hwb, nullptr, N);
    k_pool_b<<<((size_t)N * 64 + 255) / 256, 256, 0, stream>>>(hwb, off, deg, csr_src, im2b, hb, N);
  }
  k_mm<4, 2><<<gB, 256, 0, stream>>>(hb, Wto, b_out, nullptr, actb, nullptr, N);

  dim3 gp(out_size / 128, 4);
  k_graphpool_b<<<gp, 256, 0, stream>>>(actb, graph_ids, (float*)d_out, N);
}